// Round 2
// baseline (380.644 us; speedup 1.0000x reference)
//
#include <hip/hip_runtime.h>
#include <math.h>

#define N_NODES 30000
#define E_EDGES 480000
#define EP (E_EDGES + N_NODES) /* 510000 edges incl self loops */
#define IN_CH 128
#define HID 32
#define HEADS 8
#define HC 256
#define BN_EPS 1e-5f
#define NEG_SLOPE 0.2f
#define SCAN_NB ((N_NODES + 1023) / 1024) /* 30 */
#define PART_SLOTS 64 /* BN partial accumulation slots (x512 floats) */

typedef __attribute__((ext_vector_type(8))) short bf16x8;
typedef __attribute__((ext_vector_type(4))) float f32x4;

__device__ __forceinline__ float elu_f(float x) { return x > 0.f ? x : __expf(x) - 1.f; }
__device__ __forceinline__ float lrelu_f(float x) { return x >= 0.f ? x : NEG_SLOPE * x; }
__device__ __forceinline__ float bf2f(unsigned short u) {
    return __uint_as_float(((unsigned)u) << 16);
}
__device__ __forceinline__ unsigned short f2bf(float f) {
    unsigned u = __float_as_uint(f);
    return (unsigned short)((u + 0x7fffu + ((u >> 16) & 1u)) >> 16);
}

// ---------------- all weights fp32 -> bf16 transposed, one dispatch ----------------
__global__ void wt_all_kernel(const float* __restrict__ W1, const float* __restrict__ W2,
                              const float* __restrict__ lW1,
                              unsigned short* __restrict__ wt1,
                              unsigned short* __restrict__ wt2,
                              unsigned short* __restrict__ wtm) {
    int i = blockIdx.x * 256 + threadIdx.x;
    if (i < IN_CH * HC) {
        int k = i >> 8, n = i & 255;
        wt1[(size_t)n * IN_CH + k] = f2bf(W1[i]);
    } else if (i < IN_CH * HC + HC * HC) {
        int j = i - IN_CH * HC;
        int k = j >> 8, n = j & 255;
        wt2[(size_t)n * HC + k] = f2bf(W2[j]);
    } else if (i < IN_CH * HC + HC * HC + HC * HID) {
        int j = i - IN_CH * HC - HC * HC;
        int k = j >> 5, n = j & 31;
        wtm[(size_t)n * HC + k] = f2bf(lW1[j]);
    }
}

// ---------------- LDS-staged MFMA GEMM + fused al epilogue ----------------
// C[M,256] = BN(A[M,K]) * Wt^T; al_s/al_d logits computed in the epilogue.
// block = 256 thr = 4 waves; tile 64(M) x 256(N), BK=32. LDS rows padded to 40
// (2-way bank alias only = free). L2-direct fragment fetch was tried and is
// address-divergent/latency-serial (MfmaUtil stuck at 2.7%) -> keep LDS staging.
__global__ __launch_bounds__(256) void gemm_mfma(const float* __restrict__ A32,
                                                 const unsigned short* __restrict__ Abf,
                                                 const unsigned short* __restrict__ Bt,
                                                 unsigned short* __restrict__ C,
                                                 float* __restrict__ al_s,
                                                 float* __restrict__ al_d,
                                                 const float* __restrict__ a_src,
                                                 const float* __restrict__ a_dst,
                                                 int M, int K,
                                                 const float* __restrict__ sc,
                                                 const float* __restrict__ sh) {
    __shared__ __align__(16) unsigned short As[64][40];
    __shared__ __align__(16) unsigned short Bs[256][40];
    int tid = threadIdx.x;
    int wave = tid >> 6, lane = tid & 63;
    int m = lane & 15, q = lane >> 4;
    int row0 = blockIdx.x * 64;
    f32x4 acc[16];
#pragma unroll
    for (int i = 0; i < 16; ++i) acc[i] = (f32x4){0.f, 0.f, 0.f, 0.f};
    int ar = tid >> 2, aseg = tid & 3;
    for (int k0 = 0; k0 < K; k0 += 32) {
        float4 v0 = make_float4(0.f, 0.f, 0.f, 0.f), v1 = v0;
        int gr = row0 + ar;
        int c0 = k0 + aseg * 8;
        if (gr < M) {
            if (A32) {
                const float* ap = A32 + (size_t)gr * K + c0;
                v0 = *(const float4*)ap;
                v1 = *(const float4*)(ap + 4);
            } else {
                uint4 raw = *(const uint4*)(Abf + (size_t)gr * K + c0);
                v0.x = bf2f((unsigned short)raw.x); v0.y = bf2f((unsigned short)(raw.x >> 16));
                v0.z = bf2f((unsigned short)raw.y); v0.w = bf2f((unsigned short)(raw.y >> 16));
                v1.x = bf2f((unsigned short)raw.z); v1.y = bf2f((unsigned short)(raw.z >> 16));
                v1.z = bf2f((unsigned short)raw.w); v1.w = bf2f((unsigned short)(raw.w >> 16));
            }
        }
        if (sc) {
            float4 s0 = *(const float4*)(sc + c0), s1 = *(const float4*)(sc + c0 + 4);
            float4 t0 = *(const float4*)(sh + c0), t1 = *(const float4*)(sh + c0 + 4);
            v0.x = v0.x * s0.x + t0.x; v0.y = v0.y * s0.y + t0.y;
            v0.z = v0.z * s0.z + t0.z; v0.w = v0.w * s0.w + t0.w;
            v1.x = v1.x * s1.x + t1.x; v1.y = v1.y * s1.y + t1.y;
            v1.z = v1.z * s1.z + t1.z; v1.w = v1.w * s1.w + t1.w;
        }
        bf16x8 av;
        av[0] = (short)f2bf(v0.x); av[1] = (short)f2bf(v0.y);
        av[2] = (short)f2bf(v0.z); av[3] = (short)f2bf(v0.w);
        av[4] = (short)f2bf(v1.x); av[5] = (short)f2bf(v1.y);
        av[6] = (short)f2bf(v1.z); av[7] = (short)f2bf(v1.w);
        *(bf16x8*)(&As[ar][aseg * 8]) = av;
        const unsigned short* bp = Bt + (size_t)tid * K + k0;
#pragma unroll
        for (int sg = 0; sg < 4; ++sg)
            *(uint4*)(&Bs[tid][sg * 8]) = *(const uint4*)(bp + sg * 8);
        __syncthreads();
        bf16x8 a = *(const bf16x8*)(&As[wave * 16 + m][q * 8]);
#pragma unroll
        for (int nt = 0; nt < 16; ++nt) {
            bf16x8 b = *(const bf16x8*)(&Bs[nt * 16 + m][q * 8]);
            acc[nt] = __builtin_amdgcn_mfma_f32_16x16x32_bf16(a, b, acc[nt], 0, 0, 0);
        }
        __syncthreads();
    }
    // ---- epilogue: C store + per-head logits (head h = col tiles 2h,2h+1) ----
    int rbase = row0 + wave * 16;
    float asv[16], adv[16];
#pragma unroll
    for (int nt = 0; nt < 16; ++nt) {
        asv[nt] = a_src[nt * 16 + m];
        adv[nt] = a_dst[nt * 16 + m];
    }
#pragma unroll
    for (int r = 0; r < 4; ++r) {
        int grow = rbase + q * 4 + r;
        bool gv = grow < M;
        if (gv) {
#pragma unroll
            for (int nt = 0; nt < 16; ++nt)
                C[(size_t)grow * HC + nt * 16 + m] = f2bf(acc[nt][r]);
        }
#pragma unroll
        for (int h = 0; h < HEADS; ++h) {
            float ps = acc[2 * h][r] * asv[2 * h] + acc[2 * h + 1][r] * asv[2 * h + 1];
            float pd = acc[2 * h][r] * adv[2 * h] + acc[2 * h + 1][r] * adv[2 * h + 1];
            ps += __shfl_xor(ps, 1); pd += __shfl_xor(pd, 1);
            ps += __shfl_xor(ps, 2); pd += __shfl_xor(pd, 2);
            ps += __shfl_xor(ps, 4); pd += __shfl_xor(pd, 4);
            ps += __shfl_xor(ps, 8); pd += __shfl_xor(pd, 8);
            if (m == h && gv) {
                al_s[grow * HEADS + h] = ps;
                al_d[grow * HEADS + h] = pd;
            }
        }
    }
}

// ---------------- CSR build (by dst) ----------------
// Also zeroes the BN partial-sum slots (both layers) to save a dispatch.
__global__ void deg_kernel(const int* __restrict__ ei, int* __restrict__ deg,
                           float* __restrict__ part) {
    int e = blockIdx.x * blockDim.x + threadIdx.x;
    if (e < 2 * PART_SLOTS * 512) part[e] = 0.f;
    if (e >= EP) return;
    int d = (e < E_EDGES) ? ei[E_EDGES + e] : e - E_EDGES;
    atomicAdd(deg + d, 1);
}

__global__ __launch_bounds__(1024) void scan_blk(const int* __restrict__ deg,
                                                 int* __restrict__ rs,
                                                 int* __restrict__ bsum) {
    __shared__ int sh[1024];
    int t = threadIdx.x;
    int i = blockIdx.x * 1024 + t;
    int v = (i < N_NODES) ? deg[i] : 0;
    sh[t] = v;
    __syncthreads();
    for (int off = 1; off < 1024; off <<= 1) {
        int tv = (t >= off) ? sh[t - off] : 0;
        __syncthreads();
        sh[t] += tv;
        __syncthreads();
    }
    if (i < N_NODES) rs[i] = sh[t] - v;
    if (t == 1023) bsum[blockIdx.x] = sh[1023];
}

// scan_add with the top-level (30-entry) scan folded in: each block reduces
// bsum itself (removes the scan_top dispatch + its graph dependency stall).
__global__ __launch_bounds__(1024) void scan_add(int* __restrict__ rs,
                                                 int* __restrict__ cursor,
                                                 const int* __restrict__ bsum) {
    __shared__ int sh_off, sh_tot;
    int t = threadIdx.x;
    if (t < 64) {
        int v = (t < SCAN_NB) ? bsum[t] : 0;
        int pre = (t < (int)blockIdx.x) ? v : 0;
        int tot = v;
#pragma unroll
        for (int off = 1; off < 64; off <<= 1) {
            tot += __shfl_xor(tot, off);
            pre += __shfl_xor(pre, off);
        }
        if (t == 0) { sh_off = pre; sh_tot = tot; }
    }
    __syncthreads();
    int i = blockIdx.x * 1024 + t;
    if (i < N_NODES) {
        int v = rs[i] + sh_off;
        rs[i] = v;
        cursor[i] = v;
    } else if (i == N_NODES) {
        rs[N_NODES] = sh_tot;
    }
}

__global__ void scatter_kernel(const int* __restrict__ ei, int* __restrict__ cursor,
                               int* __restrict__ csr_src) {
    int e = blockIdx.x * blockDim.x + threadIdx.x;
    if (e >= EP) return;
    int s, d;
    if (e < E_EDGES) { s = ei[e]; d = ei[E_EDGES + e]; } else { s = d = e - E_EDGES; }
    int pos = atomicAdd(cursor + d, 1);
    csr_src[pos] = s;
}

// ---------------- fused softmax + aggregation + bias + ELU + BN stats ----------------
// 4 channel-quarter passes (gridDim.y): quarter p = channels 64p..64p+63 =
// head pair (2p, 2p+1). Per-pass gather working set = 30000 x 128 B = 3.84 MB,
// which fits a single XCD's 4 MB L2 -> the random gather becomes L2-resident
// instead of re-fetching the full 15.4 MB table per XCD (R1 FETCH was 117 MB =
// 8 XCDs x full table). Passes are independent; dispatch order gives temporal
// phase separation without extra kernel launches.
// Lane layout per wave (1 dst): eo = lane>>3 edge slot (8 edges/iter),
// c = lane&7 16B-chunk of the 128B quarter row. Lanes c<2 compute the edge's
// exp-logit for head 2p+c; broadcast by shfl.
__global__ __launch_bounds__(256) void attn_kernel(const uint4* __restrict__ h8,
                                                   const float* __restrict__ al_s,
                                                   const float* __restrict__ al_d,
                                                   const int* __restrict__ row_start,
                                                   const int* __restrict__ csr_src,
                                                   const float4* __restrict__ bias4,
                                                   uint4* __restrict__ out8,
                                                   float* __restrict__ part) {
    __shared__ float lds_s[4][64];
    __shared__ float lds_q[4][64];
    int wave = threadIdx.x >> 6;
    int d = blockIdx.x * 4 + wave;
    int p = blockIdx.y; /* channel quarter / head pair */
    int lane = threadIdx.x & 63;
    int eo = lane >> 3, c = lane & 7;
    int beg = row_start[d], end = row_start[d + 1];
    float ad = al_d[d * HEADS + 2 * p + (c & 1)]; /* meaningful on c<2 */
    float ssum = 0.f;
    float acc[8];
#pragma unroll
    for (int t = 0; t < 8; ++t) acc[t] = 0.f;

    const uint4* hq = h8 + (size_t)p * 8; /* quarter base within row */

    for (int i = beg; i < end; i += 8) {
        int cnt = end - i;
        if (cnt > 8) cnt = 8;
        int sidx = i + (lane & 7);
        if (sidx >= end) sidx = end - 1;
        int sv = csr_src[sidx];
        int sreg = __shfl(sv, eo); /* src of this group's edge */
        float ex = 0.f;
        if (c < 2 && eo < cnt)
            ex = __expf(lrelu_f(al_s[sreg * HEADS + 2 * p + c] + ad));
        ssum += ex;
        float aj = __shfl(ex, (lane & 56) + (c >> 2)); /* head = 2p + (c>=4) */
        if (eo < cnt) {
            uint4 v = hq[(size_t)sreg * 32 + c];
            acc[0] += aj * bf2f((unsigned short)v.x);
            acc[1] += aj * bf2f((unsigned short)(v.x >> 16));
            acc[2] += aj * bf2f((unsigned short)v.y);
            acc[3] += aj * bf2f((unsigned short)(v.y >> 16));
            acc[4] += aj * bf2f((unsigned short)v.z);
            acc[5] += aj * bf2f((unsigned short)(v.z >> 16));
            acc[6] += aj * bf2f((unsigned short)v.w);
            acc[7] += aj * bf2f((unsigned short)(v.w >> 16));
        }
    }

    /* reduce across the 8 edge-slot groups (xor bits 3..5 keep c fixed) */
    ssum += __shfl_xor(ssum, 8);
    ssum += __shfl_xor(ssum, 16);
    ssum += __shfl_xor(ssum, 32);
#pragma unroll
    for (int t = 0; t < 8; ++t) {
        acc[t] += __shfl_xor(acc[t], 8);
        acc[t] += __shfl_xor(acc[t], 16);
        acc[t] += __shfl_xor(acc[t], 32);
    }
    /* lane 0 holds head-2p denom, lane 1 holds head-2p+1 denom */
    float inv = 1.f / __shfl(ssum, c >> 2);

    float4 b0 = bias4[p * 16 + c * 2], b1 = bias4[p * 16 + c * 2 + 1];
    float o0 = elu_f(acc[0] * inv + b0.x);
    float o1 = elu_f(acc[1] * inv + b0.y);
    float o2 = elu_f(acc[2] * inv + b0.z);
    float o3 = elu_f(acc[3] * inv + b0.w);
    float o4 = elu_f(acc[4] * inv + b1.x);
    float o5 = elu_f(acc[5] * inv + b1.y);
    float o6 = elu_f(acc[6] * inv + b1.z);
    float o7 = elu_f(acc[7] * inv + b1.w);

    if (eo == 0) {
        uint4 ov;
        ov.x = (unsigned)f2bf(o0) | ((unsigned)f2bf(o1) << 16);
        ov.y = (unsigned)f2bf(o2) | ((unsigned)f2bf(o3) << 16);
        ov.z = (unsigned)f2bf(o4) | ((unsigned)f2bf(o5) << 16);
        ov.w = (unsigned)f2bf(o6) | ((unsigned)f2bf(o7) << 16);
        out8[(size_t)d * 32 + p * 8 + c] = ov;
        int cb = c * 8;
        lds_s[wave][cb + 0] = o0; lds_q[wave][cb + 0] = o0 * o0;
        lds_s[wave][cb + 1] = o1; lds_q[wave][cb + 1] = o1 * o1;
        lds_s[wave][cb + 2] = o2; lds_q[wave][cb + 2] = o2 * o2;
        lds_s[wave][cb + 3] = o3; lds_q[wave][cb + 3] = o3 * o3;
        lds_s[wave][cb + 4] = o4; lds_q[wave][cb + 4] = o4 * o4;
        lds_s[wave][cb + 5] = o5; lds_q[wave][cb + 5] = o5 * o5;
        lds_s[wave][cb + 6] = o6; lds_q[wave][cb + 6] = o6 * o6;
        lds_s[wave][cb + 7] = o7; lds_q[wave][cb + 7] = o7 * o7;
    }
    __syncthreads();
    int ch = threadIdx.x;
    if (ch < 64) {
        float s = lds_s[0][ch] + lds_s[1][ch] + lds_s[2][ch] + lds_s[3][ch];
        float q = lds_q[0][ch] + lds_q[1][ch] + lds_q[2][ch] + lds_q[3][ch];
        float* pb = part + (size_t)(blockIdx.x & (PART_SLOTS - 1)) * 512;
        atomicAdd(pb + p * 64 + ch, s);
        atomicAdd(pb + 256 + p * 64 + ch, q);
    }
}

// ---------------- BN finalize from 64 partial slots ----------------
__global__ void bn_fin_kernel(const float* __restrict__ part,
                              const float* __restrict__ g, const float* __restrict__ be,
                              float* __restrict__ scale, float* __restrict__ shift) {
    int c = threadIdx.x;
    float s = 0.f, q = 0.f;
#pragma unroll
    for (int b = 0; b < PART_SLOTS; ++b) {
        s += part[(size_t)b * 512 + c];
        q += part[(size_t)b * 512 + 256 + c];
    }
    float m = s / (float)N_NODES;
    float var = q / (float)N_NODES - m * m;
    float istd = rsqrtf(var + BN_EPS);
    float sc = istd * g[c];
    scale[c] = sc;
    shift[c] = be[c] - m * sc;
}

// ---------------- MLP head via MFMA (bf16 in, BN fused) ----------------
__global__ __launch_bounds__(256) void mlp_mfma(const unsigned short* __restrict__ in,
                                                const float* __restrict__ sc,
                                                const float* __restrict__ sh,
                                                const unsigned short* __restrict__ Wt,
                                                const float* __restrict__ lb1,
                                                const float* __restrict__ lW2,
                                                const float* __restrict__ lb2,
                                                float* __restrict__ out) {
    int tid = threadIdx.x;
    int wave = tid >> 6, lane = tid & 63;
    int m = lane & 15, q = lane >> 4;
    int rbase = blockIdx.x * 64 + wave * 16;
    int arow = rbase + m;
    bool valid = arow < N_NODES;
    const unsigned short* ap = in + (size_t)arow * HC;
    f32x4 acc0 = (f32x4){0.f, 0.f, 0.f, 0.f}, acc1 = acc0;
#pragma unroll
    for (int k0 = 0; k0 < HC; k0 += 32) {
        int c0 = k0 + q * 8;
        bf16x8 b0 = *(const bf16x8*)(Wt + (size_t)m * HC + c0);
        bf16x8 b1 = *(const bf16x8*)(Wt + (size_t)(m + 16) * HC + c0);
        bf16x8 a = (bf16x8){0, 0, 0, 0, 0, 0, 0, 0};
        if (valid) {
            uint4 raw = *(const uint4*)(ap + c0);
            float v0 = bf2f((unsigned short)raw.x), v1 = bf2f((unsigned short)(raw.x >> 16));
            float v2 = bf2f((unsigned short)raw.y), v3 = bf2f((unsigned short)(raw.y >> 16));
            float v4 = bf2f((unsigned short)raw.z), v5 = bf2f((unsigned short)(raw.z >> 16));
            float v6 = bf2f((unsigned short)raw.w), v7 = bf2f((unsigned short)(raw.w >> 16));
            float4 s0 = *(const float4*)(sc + c0), s1 = *(const float4*)(sc + c0 + 4);
            float4 t0 = *(const float4*)(sh + c0), t1 = *(const float4*)(sh + c0 + 4);
            a[0] = (short)f2bf(v0 * s0.x + t0.x);
            a[1] = (short)f2bf(v1 * s0.y + t0.y);
            a[2] = (short)f2bf(v2 * s0.z + t0.z);
            a[3] = (short)f2bf(v3 * s0.w + t0.w);
            a[4] = (short)f2bf(v4 * s1.x + t1.x);
            a[5] = (short)f2bf(v5 * s1.y + t1.y);
            a[6] = (short)f2bf(v6 * s1.z + t1.z);
            a[7] = (short)f2bf(v7 * s1.w + t1.w);
        }
        acc0 = __builtin_amdgcn_mfma_f32_16x16x32_bf16(a, b0, acc0, 0, 0, 0);
        acc1 = __builtin_amdgcn_mfma_f32_16x16x32_bf16(a, b1, acc1, 0, 0, 0);
    }
    float w2a = lW2[m], w2b = lW2[m + 16];
    float ba = lb1[m], bb = lb1[m + 16];
#pragma unroll
    for (int r = 0; r < 4; ++r) {
        float v = elu_f(acc0[r] + ba) * w2a + elu_f(acc1[r] + bb) * w2b;
        v += __shfl_xor(v, 1);
        v += __shfl_xor(v, 2);
        v += __shfl_xor(v, 4);
        v += __shfl_xor(v, 8);
        int orow = rbase + q * 4 + r;
        if (m == 0 && orow < N_NODES) out[orow] = v + lb2[0];
    }
}

extern "C" void kernel_launch(void* const* d_in, const int* in_sizes, int n_in,
                              void* d_out, int out_size, void* d_ws, size_t ws_size,
                              hipStream_t stream) {
    const float* x   = (const float*)d_in[0];
    const int*   ei  = (const int*)d_in[1];
    const float* W1  = (const float*)d_in[2];
    const float* a1s = (const float*)d_in[3];
    const float* a1d = (const float*)d_in[4];
    const float* b1  = (const float*)d_in[5];
    const float* g1  = (const float*)d_in[6];
    const float* be1 = (const float*)d_in[7];
    const float* W2  = (const float*)d_in[8];
    const float* a2s = (const float*)d_in[9];
    const float* a2d = (const float*)d_in[10];
    const float* b2  = (const float*)d_in[11];
    const float* g2  = (const float*)d_in[12];
    const float* be2 = (const float*)d_in[13];
    const float* lW1 = (const float*)d_in[14];
    const float* lb1 = (const float*)d_in[15];
    const float* lW2 = (const float*)d_in[16];
    const float* lb2 = (const float*)d_in[17];
    float* out = (float*)d_out;

    char* p = (char*)d_ws;
    auto alloc = [&](size_t bytes) {
        char* r = p;
        p += (bytes + 255) & ~(size_t)255;
        return r;
    };
    unsigned short* h_bf  = (unsigned short*)alloc((size_t)N_NODES * HC * 2);
    unsigned short* o_bf  = (unsigned short*)alloc((size_t)N_NODES * HC * 2);
    unsigned short* wt1   = (unsigned short*)alloc((size_t)IN_CH * HC * 2);
    unsigned short* wt2   = (unsigned short*)alloc((size_t)HC * HC * 2);
    unsigned short* wtm   = (unsigned short*)alloc((size_t)HC * HID * 2);
    float* f_als  = (float*)alloc((size_t)N_NODES * HEADS * 4);
    float* f_ald  = (float*)alloc((size_t)N_NODES * HEADS * 4);
    int*   i_deg  = (int*)alloc((size_t)N_NODES * 4);
    int*   i_rs   = (int*)alloc((size_t)(N_NODES + 1) * 4);
    int*   i_cur  = (int*)alloc((size_t)N_NODES * 4);
    int*   i_src  = (int*)alloc((size_t)EP * 4);
    int*   i_bsum = (int*)alloc((size_t)(SCAN_NB + 1) * 4);
    float* f_part = (float*)alloc((size_t)2 * PART_SLOTS * 512 * 4);
    float* f_sc1  = (float*)alloc(HC * 4);
    float* f_sh1  = (float*)alloc(HC * 4);
    float* f_sc2  = (float*)alloc(HC * 4);
    float* f_sh2  = (float*)alloc(HC * 4);

    int eb = (EP + 255) / 256;

    // ---- CSR build (same graph both layers); deg also zeroes BN partials ----
    hipMemsetAsync(i_deg, 0, (size_t)N_NODES * 4, stream);
    deg_kernel<<<eb, 256, 0, stream>>>(ei, i_deg, f_part);
    scan_blk<<<SCAN_NB, 1024, 0, stream>>>(i_deg, i_rs, i_bsum);
    scan_add<<<SCAN_NB, 1024, 0, stream>>>(i_rs, i_cur, i_bsum);
    scatter_kernel<<<eb, 256, 0, stream>>>(ei, i_cur, i_src);

    // ---- all weight conversions, one dispatch ----
    int wtot = IN_CH * HC + HC * HC + HC * HID;
    wt_all_kernel<<<(wtot + 255) / 256, 256, 0, stream>>>(W1, W2, lW1, wt1, wt2, wtm);

    int gblocks = (N_NODES + 63) / 64;

    auto run_layer = [&](const float* A32, const unsigned short* Abf, int K,
                         const unsigned short* wt, const float* in_sc, const float* in_sh,
                         const float* as_, const float* ad_, const float* bias,
                         const float* gam, const float* bet, float* part,
                         float* out_sc, float* out_sh) {
        gemm_mfma<<<gblocks, 256, 0, stream>>>(A32, Abf, wt, h_bf, f_als, f_ald, as_, ad_,
                                               N_NODES, K, in_sc, in_sh);
        dim3 agrid(N_NODES / 4, 4);
        attn_kernel<<<agrid, 256, 0, stream>>>((const uint4*)h_bf, f_als, f_ald,
                                               i_rs, i_src, (const float4*)bias,
                                               (uint4*)o_bf, part);
        bn_fin_kernel<<<1, 256, 0, stream>>>(part, gam, bet, out_sc, out_sh);
    };

    run_layer(x, nullptr, IN_CH, wt1, nullptr, nullptr, a1s, a1d, b1, g1, be1,
              f_part, f_sc1, f_sh1);
    run_layer(nullptr, o_bf, HC, wt2, f_sc1, f_sh1, a2s, a2d, b2, g2, be2,
              f_part + (size_t)PART_SLOTS * 512, f_sc2, f_sh2);

    mlp_mfma<<<gblocks, 256, 0, stream>>>(o_bf, f_sc2, f_sh2, wtm, lb1, lW2, lb2, out);
}

// Round 3
// 295.580 us; speedup vs baseline: 1.2878x; 1.2878x over previous
//
#include <hip/hip_runtime.h>
#include <math.h>

#define N_NODES 30000
#define E_EDGES 480000
#define EP (E_EDGES + N_NODES) /* 510000 edges incl self loops */
#define IN_CH 128
#define HID 32
#define HEADS 8
#define HC 256
#define BN_EPS 1e-5f
#define NEG_SLOPE 0.2f
#define SCAN_NB ((N_NODES + 1023) / 1024) /* 30 */
#define PART_SLOTS 64 /* BN partial accumulation slots (x512 floats) */

typedef __attribute__((ext_vector_type(8))) short bf16x8;
typedef __attribute__((ext_vector_type(4))) float f32x4;

__device__ __forceinline__ float elu_f(float x) { return x > 0.f ? x : __expf(x) - 1.f; }
__device__ __forceinline__ float lrelu_f(float x) { return x >= 0.f ? x : NEG_SLOPE * x; }
__device__ __forceinline__ float bf2f(unsigned short u) {
    return __uint_as_float(((unsigned)u) << 16);
}
__device__ __forceinline__ unsigned short f2bf(float f) {
    unsigned u = __float_as_uint(f);
    return (unsigned short)((u + 0x7fffu + ((u >> 16) & 1u)) >> 16);
}

// ---------------- all weights fp32 -> bf16 transposed, one dispatch ----------------
__global__ void wt_all_kernel(const float* __restrict__ W1, const float* __restrict__ W2,
                              const float* __restrict__ lW1,
                              unsigned short* __restrict__ wt1,
                              unsigned short* __restrict__ wt2,
                              unsigned short* __restrict__ wtm) {
    int i = blockIdx.x * 256 + threadIdx.x;
    if (i < IN_CH * HC) {
        int k = i >> 8, n = i & 255;
        wt1[(size_t)n * IN_CH + k] = f2bf(W1[i]);
    } else if (i < IN_CH * HC + HC * HC) {
        int j = i - IN_CH * HC;
        int k = j >> 8, n = j & 255;
        wt2[(size_t)n * HC + k] = f2bf(W2[j]);
    } else if (i < IN_CH * HC + HC * HC + HC * HID) {
        int j = i - IN_CH * HC - HC * HC;
        int k = j >> 5, n = j & 31;
        wtm[(size_t)n * HC + k] = f2bf(lW1[j]);
    }
}

// ---------------- LDS-staged MFMA GEMM + fused al epilogue ----------------
// C[M,256] = BN(A[M,K]) * Wt^T; al_s/al_d logits computed in the epilogue.
// block = 256 thr = 4 waves; tile 64(M) x 256(N), BK=32.
// Wave decomposition: SQUARE 4x4 sub-tile per wave (64M x 64N = cols
// wave*64..+63, all 64 rows) -> 4 A-frags + 4 B-frags feed 16 MFMAs
// (8 ds_read_b128 / K-step vs 17 in the 1x16 layout; LDS-read issue was the
// critical path). Wave w owns col tiles 4w..4w+3 = heads 2w, 2w+1, so the
// logit epilogue stays wave-local.
__global__ __launch_bounds__(256) void gemm_mfma(const float* __restrict__ A32,
                                                 const unsigned short* __restrict__ Abf,
                                                 const unsigned short* __restrict__ Bt,
                                                 unsigned short* __restrict__ C,
                                                 float* __restrict__ al_s,
                                                 float* __restrict__ al_d,
                                                 const float* __restrict__ a_src,
                                                 const float* __restrict__ a_dst,
                                                 int M, int K,
                                                 const float* __restrict__ sc,
                                                 const float* __restrict__ sh) {
    __shared__ __align__(16) unsigned short As[64][40];
    __shared__ __align__(16) unsigned short Bs[256][40];
    int tid = threadIdx.x;
    int wave = tid >> 6, lane = tid & 63;
    int m = lane & 15, q = lane >> 4;
    int row0 = blockIdx.x * 64;
    f32x4 acc[4][4];
#pragma unroll
    for (int i = 0; i < 4; ++i)
#pragma unroll
        for (int j = 0; j < 4; ++j) acc[i][j] = (f32x4){0.f, 0.f, 0.f, 0.f};
    int ar = tid >> 2, aseg = tid & 3;
    for (int k0 = 0; k0 < K; k0 += 32) {
        float4 v0 = make_float4(0.f, 0.f, 0.f, 0.f), v1 = v0;
        int gr = row0 + ar;
        int c0 = k0 + aseg * 8;
        if (gr < M) {
            if (A32) {
                const float* ap = A32 + (size_t)gr * K + c0;
                v0 = *(const float4*)ap;
                v1 = *(const float4*)(ap + 4);
            } else {
                uint4 raw = *(const uint4*)(Abf + (size_t)gr * K + c0);
                v0.x = bf2f((unsigned short)raw.x); v0.y = bf2f((unsigned short)(raw.x >> 16));
                v0.z = bf2f((unsigned short)raw.y); v0.w = bf2f((unsigned short)(raw.y >> 16));
                v1.x = bf2f((unsigned short)raw.z); v1.y = bf2f((unsigned short)(raw.z >> 16));
                v1.z = bf2f((unsigned short)raw.w); v1.w = bf2f((unsigned short)(raw.w >> 16));
            }
        }
        if (sc) {
            float4 s0 = *(const float4*)(sc + c0), s1 = *(const float4*)(sc + c0 + 4);
            float4 t0 = *(const float4*)(sh + c0), t1 = *(const float4*)(sh + c0 + 4);
            v0.x = v0.x * s0.x + t0.x; v0.y = v0.y * s0.y + t0.y;
            v0.z = v0.z * s0.z + t0.z; v0.w = v0.w * s0.w + t0.w;
            v1.x = v1.x * s1.x + t1.x; v1.y = v1.y * s1.y + t1.y;
            v1.z = v1.z * s1.z + t1.z; v1.w = v1.w * s1.w + t1.w;
        }
        bf16x8 av;
        av[0] = (short)f2bf(v0.x); av[1] = (short)f2bf(v0.y);
        av[2] = (short)f2bf(v0.z); av[3] = (short)f2bf(v0.w);
        av[4] = (short)f2bf(v1.x); av[5] = (short)f2bf(v1.y);
        av[6] = (short)f2bf(v1.z); av[7] = (short)f2bf(v1.w);
        *(bf16x8*)(&As[ar][aseg * 8]) = av;
        const unsigned short* bp = Bt + (size_t)tid * K + k0;
#pragma unroll
        for (int sg = 0; sg < 4; ++sg)
            *(uint4*)(&Bs[tid][sg * 8]) = *(const uint4*)(bp + sg * 8);
        __syncthreads();
        bf16x8 a0 = *(const bf16x8*)(&As[m][q * 8]);
        bf16x8 a1 = *(const bf16x8*)(&As[16 + m][q * 8]);
        bf16x8 a2 = *(const bf16x8*)(&As[32 + m][q * 8]);
        bf16x8 a3 = *(const bf16x8*)(&As[48 + m][q * 8]);
#pragma unroll
        for (int ni = 0; ni < 4; ++ni) {
            bf16x8 b = *(const bf16x8*)(&Bs[(wave * 4 + ni) * 16 + m][q * 8]);
            acc[0][ni] = __builtin_amdgcn_mfma_f32_16x16x32_bf16(a0, b, acc[0][ni], 0, 0, 0);
            acc[1][ni] = __builtin_amdgcn_mfma_f32_16x16x32_bf16(a1, b, acc[1][ni], 0, 0, 0);
            acc[2][ni] = __builtin_amdgcn_mfma_f32_16x16x32_bf16(a2, b, acc[2][ni], 0, 0, 0);
            acc[3][ni] = __builtin_amdgcn_mfma_f32_16x16x32_bf16(a3, b, acc[3][ni], 0, 0, 0);
        }
        __syncthreads();
    }
    // ---- epilogue: C store + per-head logits (wave w -> heads 2w, 2w+1) ----
    int col0 = wave * 64;
    float asv[4], adv[4];
#pragma unroll
    for (int ni = 0; ni < 4; ++ni) {
        asv[ni] = a_src[col0 + ni * 16 + m];
        adv[ni] = a_dst[col0 + ni * 16 + m];
    }
#pragma unroll
    for (int mi = 0; mi < 4; ++mi) {
#pragma unroll
        for (int r = 0; r < 4; ++r) {
            int grow = row0 + mi * 16 + q * 4 + r;
            bool gv = grow < M;
            if (gv) {
#pragma unroll
                for (int ni = 0; ni < 4; ++ni)
                    C[(size_t)grow * HC + col0 + ni * 16 + m] = f2bf(acc[mi][ni][r]);
            }
            float ps0 = acc[mi][0][r] * asv[0] + acc[mi][1][r] * asv[1];
            float pd0 = acc[mi][0][r] * adv[0] + acc[mi][1][r] * adv[1];
            float ps1 = acc[mi][2][r] * asv[2] + acc[mi][3][r] * asv[3];
            float pd1 = acc[mi][2][r] * adv[2] + acc[mi][3][r] * adv[3];
            ps0 += __shfl_xor(ps0, 1); pd0 += __shfl_xor(pd0, 1);
            ps1 += __shfl_xor(ps1, 1); pd1 += __shfl_xor(pd1, 1);
            ps0 += __shfl_xor(ps0, 2); pd0 += __shfl_xor(pd0, 2);
            ps1 += __shfl_xor(ps1, 2); pd1 += __shfl_xor(pd1, 2);
            ps0 += __shfl_xor(ps0, 4); pd0 += __shfl_xor(pd0, 4);
            ps1 += __shfl_xor(ps1, 4); pd1 += __shfl_xor(pd1, 4);
            ps0 += __shfl_xor(ps0, 8); pd0 += __shfl_xor(pd0, 8);
            ps1 += __shfl_xor(ps1, 8); pd1 += __shfl_xor(pd1, 8);
            if (gv) {
                if (m == 0) {
                    al_s[grow * HEADS + 2 * wave] = ps0;
                    al_d[grow * HEADS + 2 * wave] = pd0;
                } else if (m == 1) {
                    al_s[grow * HEADS + 2 * wave + 1] = ps1;
                    al_d[grow * HEADS + 2 * wave + 1] = pd1;
                }
            }
        }
    }
}

// ---------------- CSR build (by dst) ----------------
// Also zeroes the BN partial-sum slots (both layers) to save a dispatch.
__global__ void deg_kernel(const int* __restrict__ ei, int* __restrict__ deg,
                           float* __restrict__ part) {
    int e = blockIdx.x * blockDim.x + threadIdx.x;
    if (e < 2 * PART_SLOTS * 512) part[e] = 0.f;
    if (e >= EP) return;
    int d = (e < E_EDGES) ? ei[E_EDGES + e] : e - E_EDGES;
    atomicAdd(deg + d, 1);
}

__global__ __launch_bounds__(1024) void scan_blk(const int* __restrict__ deg,
                                                 int* __restrict__ rs,
                                                 int* __restrict__ bsum) {
    __shared__ int sh[1024];
    int t = threadIdx.x;
    int i = blockIdx.x * 1024 + t;
    int v = (i < N_NODES) ? deg[i] : 0;
    sh[t] = v;
    __syncthreads();
    for (int off = 1; off < 1024; off <<= 1) {
        int tv = (t >= off) ? sh[t - off] : 0;
        __syncthreads();
        sh[t] += tv;
        __syncthreads();
    }
    if (i < N_NODES) rs[i] = sh[t] - v;
    if (t == 1023) bsum[blockIdx.x] = sh[1023];
}

// scan_add with the top-level (30-entry) scan folded in: each block reduces
// bsum itself (removes the scan_top dispatch + its graph dependency stall).
__global__ __launch_bounds__(1024) void scan_add(int* __restrict__ rs,
                                                 int* __restrict__ cursor,
                                                 const int* __restrict__ bsum) {
    __shared__ int sh_off, sh_tot;
    int t = threadIdx.x;
    if (t < 64) {
        int v = (t < SCAN_NB) ? bsum[t] : 0;
        int pre = (t < (int)blockIdx.x) ? v : 0;
        int tot = v;
#pragma unroll
        for (int off = 1; off < 64; off <<= 1) {
            tot += __shfl_xor(tot, off);
            pre += __shfl_xor(pre, off);
        }
        if (t == 0) { sh_off = pre; sh_tot = tot; }
    }
    __syncthreads();
    int i = blockIdx.x * 1024 + t;
    if (i < N_NODES) {
        int v = rs[i] + sh_off;
        rs[i] = v;
        cursor[i] = v;
    } else if (i == N_NODES) {
        rs[N_NODES] = sh_tot;
    }
}

__global__ void scatter_kernel(const int* __restrict__ ei, int* __restrict__ cursor,
                               int* __restrict__ csr_src) {
    int e = blockIdx.x * blockDim.x + threadIdx.x;
    if (e >= EP) return;
    int s, d;
    if (e < E_EDGES) { s = ei[e]; d = ei[E_EDGES + e]; } else { s = d = e - E_EDGES; }
    int pos = atomicAdd(cursor + d, 1);
    csr_src[pos] = s;
}

// ---------------- fused softmax + aggregation + bias + ELU + BN stats ----------------
// (R1-verified version: 47 us. R2's channel-quarter split regressed to 88 us --
// it broke memory-level parallelism: 1 dependent gather/iter vs 4 independent
// ones here, and 4x edge-visit overhead. Keep this structure.)
// Wave per dst. Gather 16B/lane (uint4 = 8 channels): lanes split by edge
// parity g = lane>>5, each half-wave owns one edge of a pair -> 1 KB per wave
// load instr (2 edges). Parity halves combined with one shfl_xor(32).
// BN sum/sumsq from pre-bf16 f32 outputs, block-reduced in LDS, atomically
// accumulated into 64 partial slots.
__global__ __launch_bounds__(256) void attn_kernel(const uint4* __restrict__ h8,
                                                   const float* __restrict__ al_s,
                                                   const float* __restrict__ al_d,
                                                   const int* __restrict__ row_start,
                                                   const int* __restrict__ csr_src,
                                                   const float4* __restrict__ bias4,
                                                   uint4* __restrict__ out8,
                                                   float* __restrict__ part) {
    __shared__ float lds_s[4][256];
    __shared__ float lds_q[4][256];
    int wave = threadIdx.x >> 6;
    int d = blockIdx.x * 4 + wave;
    int lane = threadIdx.x & 63;
    int hh = lane & 7, eo = lane >> 3;     // logit lanes: edge eo, head hh
    int g = lane >> 5, c = lane & 31;      // agg lanes: parity g, uint4-chunk c
    int hl = c >> 2;                       // head owning channels 8c..8c+7
    int beg = row_start[d], end = row_start[d + 1];
    float ad = al_d[d * HEADS + hh];
    float ssum = 0.f;
    float acc[8];
#pragma unroll
    for (int t = 0; t < 8; ++t) acc[t] = 0.f;

#define PAIR_BODY(p)                                                      \
    {                                                                     \
        int e0 = 2 * (p) + g;                                             \
        int sj = __shfl(sreg, e0 * 8);                                    \
        float aj = __shfl(ex, e0 * 8 + hl);                               \
        uint4 v = h8[(size_t)sj * 32 + c];                                \
        acc[0] += aj * bf2f((unsigned short)v.x);                         \
        acc[1] += aj * bf2f((unsigned short)(v.x >> 16));                 \
        acc[2] += aj * bf2f((unsigned short)v.y);                         \
        acc[3] += aj * bf2f((unsigned short)(v.y >> 16));                 \
        acc[4] += aj * bf2f((unsigned short)v.z);                         \
        acc[5] += aj * bf2f((unsigned short)(v.z >> 16));                 \
        acc[6] += aj * bf2f((unsigned short)v.w);                         \
        acc[7] += aj * bf2f((unsigned short)(v.w >> 16));                 \
    }

    for (int i = beg; i < end; i += 8) {
        int chunk = end - i;
        if (chunk > 8) chunk = 8;
        int sreg = 0;
        float ex = 0.f;
        if (eo < chunk) {
            sreg = csr_src[i + eo];
            ex = __expf(lrelu_f(al_s[sreg * HEADS + hh] + ad));
        }
        ssum += ex;
        if (chunk == 8) {
#pragma unroll
            for (int p = 0; p < 4; ++p) PAIR_BODY(p);
        } else {
            int np = (chunk + 1) >> 1;  // odd tail: g=1 lane reads ex=0 -> no-op
            for (int p = 0; p < np; ++p) PAIR_BODY(p);
        }
    }
#undef PAIR_BODY

    // combine edge-parity halves; both halves end with identical acc
#pragma unroll
    for (int t = 0; t < 8; ++t) acc[t] += __shfl_xor(acc[t], 32);
    ssum += __shfl_xor(ssum, 8);
    ssum += __shfl_xor(ssum, 16);
    ssum += __shfl_xor(ssum, 32);
    float inv = 1.f / __shfl(ssum, hl);

    float4 b0 = bias4[c * 2], b1 = bias4[c * 2 + 1];
    float o0 = elu_f(acc[0] * inv + b0.x);
    float o1 = elu_f(acc[1] * inv + b0.y);
    float o2 = elu_f(acc[2] * inv + b0.z);
    float o3 = elu_f(acc[3] * inv + b0.w);
    float o4 = elu_f(acc[4] * inv + b1.x);
    float o5 = elu_f(acc[5] * inv + b1.y);
    float o6 = elu_f(acc[6] * inv + b1.z);
    float o7 = elu_f(acc[7] * inv + b1.w);

    if (g == 0) {
        uint4 ov;
        ov.x = (unsigned)f2bf(o0) | ((unsigned)f2bf(o1) << 16);
        ov.y = (unsigned)f2bf(o2) | ((unsigned)f2bf(o3) << 16);
        ov.z = (unsigned)f2bf(o4) | ((unsigned)f2bf(o5) << 16);
        ov.w = (unsigned)f2bf(o6) | ((unsigned)f2bf(o7) << 16);
        out8[(size_t)d * 32 + c] = ov;
        int cb = c * 8;
        lds_s[wave][cb + 0] = o0; lds_q[wave][cb + 0] = o0 * o0;
        lds_s[wave][cb + 1] = o1; lds_q[wave][cb + 1] = o1 * o1;
        lds_s[wave][cb + 2] = o2; lds_q[wave][cb + 2] = o2 * o2;
        lds_s[wave][cb + 3] = o3; lds_q[wave][cb + 3] = o3 * o3;
        lds_s[wave][cb + 4] = o4; lds_q[wave][cb + 4] = o4 * o4;
        lds_s[wave][cb + 5] = o5; lds_q[wave][cb + 5] = o5 * o5;
        lds_s[wave][cb + 6] = o6; lds_q[wave][cb + 6] = o6 * o6;
        lds_s[wave][cb + 7] = o7; lds_q[wave][cb + 7] = o7 * o7;
    }
    __syncthreads();
    int ch = threadIdx.x;
    float s = lds_s[0][ch] + lds_s[1][ch] + lds_s[2][ch] + lds_s[3][ch];
    float q = lds_q[0][ch] + lds_q[1][ch] + lds_q[2][ch] + lds_q[3][ch];
    float* pb = part + (size_t)(blockIdx.x & (PART_SLOTS - 1)) * 512;
    atomicAdd(pb + ch, s);
    atomicAdd(pb + 256 + ch, q);
}

// ---------------- BN finalize from 64 partial slots ----------------
__global__ void bn_fin_kernel(const float* __restrict__ part,
                              const float* __restrict__ g, const float* __restrict__ be,
                              float* __restrict__ scale, float* __restrict__ shift) {
    int c = threadIdx.x;
    float s = 0.f, q = 0.f;
#pragma unroll
    for (int b = 0; b < PART_SLOTS; ++b) {
        s += part[(size_t)b * 512 + c];
        q += part[(size_t)b * 512 + 256 + c];
    }
    float m = s / (float)N_NODES;
    float var = q / (float)N_NODES - m * m;
    float istd = rsqrtf(var + BN_EPS);
    float sc = istd * g[c];
    scale[c] = sc;
    shift[c] = be[c] - m * sc;
}

// ---------------- MLP head via MFMA (bf16 in, BN fused) ----------------
__global__ __launch_bounds__(256) void mlp_mfma(const unsigned short* __restrict__ in,
                                                const float* __restrict__ sc,
                                                const float* __restrict__ sh,
                                                const unsigned short* __restrict__ Wt,
                                                const float* __restrict__ lb1,
                                                const float* __restrict__ lW2,
                                                const float* __restrict__ lb2,
                                                float* __restrict__ out) {
    int tid = threadIdx.x;
    int wave = tid >> 6, lane = tid & 63;
    int m = lane & 15, q = lane >> 4;
    int rbase = blockIdx.x * 64 + wave * 16;
    int arow = rbase + m;
    bool valid = arow < N_NODES;
    const unsigned short* ap = in + (size_t)arow * HC;
    f32x4 acc0 = (f32x4){0.f, 0.f, 0.f, 0.f}, acc1 = acc0;
#pragma unroll
    for (int k0 = 0; k0 < HC; k0 += 32) {
        int c0 = k0 + q * 8;
        bf16x8 b0 = *(const bf16x8*)(Wt + (size_t)m * HC + c0);
        bf16x8 b1 = *(const bf16x8*)(Wt + (size_t)(m + 16) * HC + c0);
        bf16x8 a = (bf16x8){0, 0, 0, 0, 0, 0, 0, 0};
        if (valid) {
            uint4 raw = *(const uint4*)(ap + c0);
            float v0 = bf2f((unsigned short)raw.x), v1 = bf2f((unsigned short)(raw.x >> 16));
            float v2 = bf2f((unsigned short)raw.y), v3 = bf2f((unsigned short)(raw.y >> 16));
            float v4 = bf2f((unsigned short)raw.z), v5 = bf2f((unsigned short)(raw.z >> 16));
            float v6 = bf2f((unsigned short)raw.w), v7 = bf2f((unsigned short)(raw.w >> 16));
            float4 s0 = *(const float4*)(sc + c0), s1 = *(const float4*)(sc + c0 + 4);
            float4 t0 = *(const float4*)(sh + c0), t1 = *(const float4*)(sh + c0 + 4);
            a[0] = (short)f2bf(v0 * s0.x + t0.x);
            a[1] = (short)f2bf(v1 * s0.y + t0.y);
            a[2] = (short)f2bf(v2 * s0.z + t0.z);
            a[3] = (short)f2bf(v3 * s0.w + t0.w);
            a[4] = (short)f2bf(v4 * s1.x + t1.x);
            a[5] = (short)f2bf(v5 * s1.y + t1.y);
            a[6] = (short)f2bf(v6 * s1.z + t1.z);
            a[7] = (short)f2bf(v7 * s1.w + t1.w);
        }
        acc0 = __builtin_amdgcn_mfma_f32_16x16x32_bf16(a, b0, acc0, 0, 0, 0);
        acc1 = __builtin_amdgcn_mfma_f32_16x16x32_bf16(a, b1, acc1, 0, 0, 0);
    }
    float w2a = lW2[m], w2b = lW2[m + 16];
    float ba = lb1[m], bb = lb1[m + 16];
#pragma unroll
    for (int r = 0; r < 4; ++r) {
        float v = elu_f(acc0[r] + ba) * w2a + elu_f(acc1[r] + bb) * w2b;
        v += __shfl_xor(v, 1);
        v += __shfl_xor(v, 2);
        v += __shfl_xor(v, 4);
        v += __shfl_xor(v, 8);
        int orow = rbase + q * 4 + r;
        if (m == 0 && orow < N_NODES) out[orow] = v + lb2[0];
    }
}

extern "C" void kernel_launch(void* const* d_in, const int* in_sizes, int n_in,
                              void* d_out, int out_size, void* d_ws, size_t ws_size,
                              hipStream_t stream) {
    const float* x   = (const float*)d_in[0];
    const int*   ei  = (const int*)d_in[1];
    const float* W1  = (const float*)d_in[2];
    const float* a1s = (const float*)d_in[3];
    const float* a1d = (const float*)d_in[4];
    const float* b1  = (const float*)d_in[5];
    const float* g1  = (const float*)d_in[6];
    const float* be1 = (const float*)d_in[7];
    const float* W2  = (const float*)d_in[8];
    const float* a2s = (const float*)d_in[9];
    const float* a2d = (const float*)d_in[10];
    const float* b2  = (const float*)d_in[11];
    const float* g2  = (const float*)d_in[12];
    const float* be2 = (const float*)d_in[13];
    const float* lW1 = (const float*)d_in[14];
    const float* lb1 = (const float*)d_in[15];
    const float* lW2 = (const float*)d_in[16];
    const float* lb2 = (const float*)d_in[17];
    float* out = (float*)d_out;

    char* p = (char*)d_ws;
    auto alloc = [&](size_t bytes) {
        char* r = p;
        p += (bytes + 255) & ~(size_t)255;
        return r;
    };
    unsigned short* h_bf  = (unsigned short*)alloc((size_t)N_NODES * HC * 2);
    unsigned short* o_bf  = (unsigned short*)alloc((size_t)N_NODES * HC * 2);
    unsigned short* wt1   = (unsigned short*)alloc((size_t)IN_CH * HC * 2);
    unsigned short* wt2   = (unsigned short*)alloc((size_t)HC * HC * 2);
    unsigned short* wtm   = (unsigned short*)alloc((size_t)HC * HID * 2);
    float* f_als  = (float*)alloc((size_t)N_NODES * HEADS * 4);
    float* f_ald  = (float*)alloc((size_t)N_NODES * HEADS * 4);
    int*   i_deg  = (int*)alloc((size_t)N_NODES * 4);
    int*   i_rs   = (int*)alloc((size_t)(N_NODES + 1) * 4);
    int*   i_cur  = (int*)alloc((size_t)N_NODES * 4);
    int*   i_src  = (int*)alloc((size_t)EP * 4);
    int*   i_bsum = (int*)alloc((size_t)(SCAN_NB + 1) * 4);
    float* f_part = (float*)alloc((size_t)2 * PART_SLOTS * 512 * 4);
    float* f_sc1  = (float*)alloc(HC * 4);
    float* f_sh1  = (float*)alloc(HC * 4);
    float* f_sc2  = (float*)alloc(HC * 4);
    float* f_sh2  = (float*)alloc(HC * 4);

    int eb = (EP + 255) / 256;

    // ---- CSR build (same graph both layers); deg also zeroes BN partials ----
    hipMemsetAsync(i_deg, 0, (size_t)N_NODES * 4, stream);
    deg_kernel<<<eb, 256, 0, stream>>>(ei, i_deg, f_part);
    scan_blk<<<SCAN_NB, 1024, 0, stream>>>(i_deg, i_rs, i_bsum);
    scan_add<<<SCAN_NB, 1024, 0, stream>>>(i_rs, i_cur, i_bsum);
    scatter_kernel<<<eb, 256, 0, stream>>>(ei, i_cur, i_src);

    // ---- all weight conversions, one dispatch ----
    int wtot = IN_CH * HC + HC * HC + HC * HID;
    wt_all_kernel<<<(wtot + 255) / 256, 256, 0, stream>>>(W1, W2, lW1, wt1, wt2, wtm);

    int gblocks = (N_NODES + 63) / 64;

    auto run_layer = [&](const float* A32, const unsigned short* Abf, int K,
                         const unsigned short* wt, const float* in_sc, const float* in_sh,
                         const float* as_, const float* ad_, const float* bias,
                         const float* gam, const float* bet, float* part,
                         float* out_sc, float* out_sh) {
        gemm_mfma<<<gblocks, 256, 0, stream>>>(A32, Abf, wt, h_bf, f_als, f_ald, as_, ad_,
                                               N_NODES, K, in_sc, in_sh);
        attn_kernel<<<N_NODES / 4, 256, 0, stream>>>((const uint4*)h_bf, f_als, f_ald,
                                                     i_rs, i_src, (const float4*)bias,
                                                     (uint4*)o_bf, part);
        bn_fin_kernel<<<1, 256, 0, stream>>>(part, gam, bet, out_sc, out_sh);
    };

    run_layer(x, nullptr, IN_CH, wt1, nullptr, nullptr, a1s, a1d, b1, g1, be1,
              f_part, f_sc1, f_sh1);
    run_layer(nullptr, o_bf, HC, wt2, f_sc1, f_sh1, a2s, a2d, b2, g2, be2,
              f_part + (size_t)PART_SLOTS * 512, f_sc2, f_sh2);

    mlp_mfma<<<gblocks, 256, 0, stream>>>(o_bf, f_sc2, f_sh2, wtm, lb1, lW2, lb2, out);
}

// Round 4
// 295.314 us; speedup vs baseline: 1.2889x; 1.0009x over previous
//
#include <hip/hip_runtime.h>
#include <math.h>

#define N_NODES 30000
#define E_EDGES 480000
#define EP (E_EDGES + N_NODES) /* 510000 edges incl self loops */
#define IN_CH 128
#define HID 32
#define HEADS 8
#define HC 256
#define BN_EPS 1e-5f
#define NEG_SLOPE 0.2f
#define SCAN_NB ((N_NODES + 1023) / 1024) /* 30 */
#define PART_SLOTS 64 /* BN partial accumulation slots (x512 floats) */

typedef __attribute__((ext_vector_type(8))) short bf16x8;
typedef __attribute__((ext_vector_type(4))) float f32x4;

__device__ __forceinline__ float elu_f(float x) { return x > 0.f ? x : __expf(x) - 1.f; }
__device__ __forceinline__ float lrelu_f(float x) { return x >= 0.f ? x : NEG_SLOPE * x; }
__device__ __forceinline__ float bf2f(unsigned short u) {
    return __uint_as_float(((unsigned)u) << 16);
}
__device__ __forceinline__ unsigned short f2bf(float f) {
    unsigned u = __float_as_uint(f);
    return (unsigned short)((u + 0x7fffu + ((u >> 16) & 1u)) >> 16);
}

// ---------------- all weights fp32 -> bf16 transposed, one dispatch ----------------
__global__ void wt_all_kernel(const float* __restrict__ W1, const float* __restrict__ W2,
                              const float* __restrict__ lW1,
                              unsigned short* __restrict__ wt1,
                              unsigned short* __restrict__ wt2,
                              unsigned short* __restrict__ wtm) {
    int i = blockIdx.x * 256 + threadIdx.x;
    if (i < IN_CH * HC) {
        int k = i >> 8, n = i & 255;
        wt1[(size_t)n * IN_CH + k] = f2bf(W1[i]);
    } else if (i < IN_CH * HC + HC * HC) {
        int j = i - IN_CH * HC;
        int k = j >> 8, n = j & 255;
        wt2[(size_t)n * HC + k] = f2bf(W2[j]);
    } else if (i < IN_CH * HC + HC * HC + HC * HID) {
        int j = i - IN_CH * HC - HC * HC;
        int k = j >> 5, n = j & 31;
        wtm[(size_t)n * HC + k] = f2bf(lW1[j]);
    }
}

// ---------------- LDS-staged MFMA GEMM + fused al epilogue + fused BN-finalize --------
// C[M,256] = BN(A[M,K]) * Wt^T. 512 thr = 8 waves as 2(M)x4(N); tile 128(M) x 256(N),
// BK=32. Per-wave sub-tile 64x64 (4x4 frags) -- identical verified math/indexing as R3,
// with wave row offset wr and halved B-staging/barrier overhead per output row.
// BN scale/shift computed IN-KERNEL from the 64 partial slots (bn_fin dispatch removed).
__global__ __launch_bounds__(512) void gemm_mfma(const float* __restrict__ A32,
                                                 const unsigned short* __restrict__ Abf,
                                                 const unsigned short* __restrict__ Bt,
                                                 unsigned short* __restrict__ C,
                                                 float* __restrict__ al_s,
                                                 float* __restrict__ al_d,
                                                 const float* __restrict__ a_src,
                                                 const float* __restrict__ a_dst,
                                                 int M, int K,
                                                 const float* __restrict__ part,
                                                 const float* __restrict__ gam,
                                                 const float* __restrict__ bet) {
    __shared__ __align__(16) unsigned short As[128][40];
    __shared__ __align__(16) unsigned short Bs[256][40];
    __shared__ float scs[HC], shs[HC];
    int tid = threadIdx.x;
    int wave = tid >> 6, lane = tid & 63;
    int m = lane & 15, q = lane >> 4;
    int wr = (wave >> 2) * 64;  /* wave row offset in tile */
    int hp = wave & 3;          /* head-pair / col group   */
    int col0 = hp * 64;
    int row0 = blockIdx.x * 128;
    bool haveBN = (part != nullptr);
    if (haveBN && tid < HC) {
        int c = tid;
        float s = 0.f, qq = 0.f;
#pragma unroll
        for (int b = 0; b < PART_SLOTS; ++b) {
            s += part[(size_t)b * 512 + c];
            qq += part[(size_t)b * 512 + 256 + c];
        }
        float mn = s / (float)N_NODES;
        float var = qq / (float)N_NODES - mn * mn;
        float istd = rsqrtf(var + BN_EPS);
        float sc = istd * gam[c];
        scs[c] = sc;
        shs[c] = bet[c] - mn * sc;
    }
    __syncthreads();

    f32x4 acc[4][4];
#pragma unroll
    for (int i = 0; i < 4; ++i)
#pragma unroll
        for (int j = 0; j < 4; ++j) acc[i][j] = (f32x4){0.f, 0.f, 0.f, 0.f};
    int ar = tid >> 2, aseg = tid & 3;          /* A: 128 rows x 4 col-segments */
    int br = tid >> 1, bseg = tid & 1;          /* B: 256 rows x 2 col-halves  */
    for (int k0 = 0; k0 < K; k0 += 32) {
        float4 v0 = make_float4(0.f, 0.f, 0.f, 0.f), v1 = v0;
        int gr = row0 + ar;
        int c0 = k0 + aseg * 8;
        if (gr < M) {
            if (A32) {
                const float* ap = A32 + (size_t)gr * K + c0;
                v0 = *(const float4*)ap;
                v1 = *(const float4*)(ap + 4);
            } else {
                uint4 raw = *(const uint4*)(Abf + (size_t)gr * K + c0);
                v0.x = bf2f((unsigned short)raw.x); v0.y = bf2f((unsigned short)(raw.x >> 16));
                v0.z = bf2f((unsigned short)raw.y); v0.w = bf2f((unsigned short)(raw.y >> 16));
                v1.x = bf2f((unsigned short)raw.z); v1.y = bf2f((unsigned short)(raw.z >> 16));
                v1.z = bf2f((unsigned short)raw.w); v1.w = bf2f((unsigned short)(raw.w >> 16));
            }
        }
        if (haveBN) {
            float4 s0 = *(const float4*)(scs + c0), s1 = *(const float4*)(scs + c0 + 4);
            float4 t0 = *(const float4*)(shs + c0), t1 = *(const float4*)(shs + c0 + 4);
            v0.x = v0.x * s0.x + t0.x; v0.y = v0.y * s0.y + t0.y;
            v0.z = v0.z * s0.z + t0.z; v0.w = v0.w * s0.w + t0.w;
            v1.x = v1.x * s1.x + t1.x; v1.y = v1.y * s1.y + t1.y;
            v1.z = v1.z * s1.z + t1.z; v1.w = v1.w * s1.w + t1.w;
        }
        bf16x8 av;
        av[0] = (short)f2bf(v0.x); av[1] = (short)f2bf(v0.y);
        av[2] = (short)f2bf(v0.z); av[3] = (short)f2bf(v0.w);
        av[4] = (short)f2bf(v1.x); av[5] = (short)f2bf(v1.y);
        av[6] = (short)f2bf(v1.z); av[7] = (short)f2bf(v1.w);
        *(bf16x8*)(&As[ar][aseg * 8]) = av;
        const unsigned short* bp = Bt + (size_t)br * K + k0 + bseg * 16;
        *(uint4*)(&Bs[br][bseg * 16]) = *(const uint4*)bp;
        *(uint4*)(&Bs[br][bseg * 16 + 8]) = *(const uint4*)(bp + 8);
        __syncthreads();
        bf16x8 a0 = *(const bf16x8*)(&As[wr + m][q * 8]);
        bf16x8 a1 = *(const bf16x8*)(&As[wr + 16 + m][q * 8]);
        bf16x8 a2 = *(const bf16x8*)(&As[wr + 32 + m][q * 8]);
        bf16x8 a3 = *(const bf16x8*)(&As[wr + 48 + m][q * 8]);
#pragma unroll
        for (int ni = 0; ni < 4; ++ni) {
            bf16x8 b = *(const bf16x8*)(&Bs[col0 + ni * 16 + m][q * 8]);
            acc[0][ni] = __builtin_amdgcn_mfma_f32_16x16x32_bf16(a0, b, acc[0][ni], 0, 0, 0);
            acc[1][ni] = __builtin_amdgcn_mfma_f32_16x16x32_bf16(a1, b, acc[1][ni], 0, 0, 0);
            acc[2][ni] = __builtin_amdgcn_mfma_f32_16x16x32_bf16(a2, b, acc[2][ni], 0, 0, 0);
            acc[3][ni] = __builtin_amdgcn_mfma_f32_16x16x32_bf16(a3, b, acc[3][ni], 0, 0, 0);
        }
        __syncthreads();
    }
    // ---- epilogue: C store + per-head logits (col group hp -> heads 2hp, 2hp+1) ----
    float asv[4], adv[4];
#pragma unroll
    for (int ni = 0; ni < 4; ++ni) {
        asv[ni] = a_src[col0 + ni * 16 + m];
        adv[ni] = a_dst[col0 + ni * 16 + m];
    }
#pragma unroll
    for (int mi = 0; mi < 4; ++mi) {
#pragma unroll
        for (int r = 0; r < 4; ++r) {
            int grow = row0 + wr + mi * 16 + q * 4 + r;
            bool gv = grow < M;
            if (gv) {
#pragma unroll
                for (int ni = 0; ni < 4; ++ni)
                    C[(size_t)grow * HC + col0 + ni * 16 + m] = f2bf(acc[mi][ni][r]);
            }
            float ps0 = acc[mi][0][r] * asv[0] + acc[mi][1][r] * asv[1];
            float pd0 = acc[mi][0][r] * adv[0] + acc[mi][1][r] * adv[1];
            float ps1 = acc[mi][2][r] * asv[2] + acc[mi][3][r] * asv[3];
            float pd1 = acc[mi][2][r] * adv[2] + acc[mi][3][r] * adv[3];
            ps0 += __shfl_xor(ps0, 1); pd0 += __shfl_xor(pd0, 1);
            ps1 += __shfl_xor(ps1, 1); pd1 += __shfl_xor(pd1, 1);
            ps0 += __shfl_xor(ps0, 2); pd0 += __shfl_xor(pd0, 2);
            ps1 += __shfl_xor(ps1, 2); pd1 += __shfl_xor(pd1, 2);
            ps0 += __shfl_xor(ps0, 4); pd0 += __shfl_xor(pd0, 4);
            ps1 += __shfl_xor(ps1, 4); pd1 += __shfl_xor(pd1, 4);
            ps0 += __shfl_xor(ps0, 8); pd0 += __shfl_xor(pd0, 8);
            ps1 += __shfl_xor(ps1, 8); pd1 += __shfl_xor(pd1, 8);
            if (gv) {
                if (m == 0) {
                    al_s[grow * HEADS + 2 * hp] = ps0;
                    al_d[grow * HEADS + 2 * hp] = pd0;
                } else if (m == 1) {
                    al_s[grow * HEADS + 2 * hp + 1] = ps1;
                    al_d[grow * HEADS + 2 * hp + 1] = pd1;
                }
            }
        }
    }
}

// ---------------- CSR build (by dst) ----------------
// Also zeroes the BN partial-sum slots (both layers) to save a dispatch.
__global__ void deg_kernel(const int* __restrict__ ei, int* __restrict__ deg,
                           float* __restrict__ part) {
    int e = blockIdx.x * blockDim.x + threadIdx.x;
    if (e < 2 * PART_SLOTS * 512) part[e] = 0.f;
    if (e >= EP) return;
    int d = (e < E_EDGES) ? ei[E_EDGES + e] : e - E_EDGES;
    atomicAdd(deg + d, 1);
}

__global__ __launch_bounds__(1024) void scan_blk(const int* __restrict__ deg,
                                                 int* __restrict__ rs,
                                                 int* __restrict__ bsum) {
    __shared__ int sh[1024];
    int t = threadIdx.x;
    int i = blockIdx.x * 1024 + t;
    int v = (i < N_NODES) ? deg[i] : 0;
    sh[t] = v;
    __syncthreads();
    for (int off = 1; off < 1024; off <<= 1) {
        int tv = (t >= off) ? sh[t - off] : 0;
        __syncthreads();
        sh[t] += tv;
        __syncthreads();
    }
    if (i < N_NODES) rs[i] = sh[t] - v;
    if (t == 1023) bsum[blockIdx.x] = sh[1023];
}

// scan_add with the top-level (30-entry) scan folded in.
__global__ __launch_bounds__(1024) void scan_add(int* __restrict__ rs,
                                                 int* __restrict__ cursor,
                                                 const int* __restrict__ bsum) {
    __shared__ int sh_off, sh_tot;
    int t = threadIdx.x;
    if (t < 64) {
        int v = (t < SCAN_NB) ? bsum[t] : 0;
        int pre = (t < (int)blockIdx.x) ? v : 0;
        int tot = v;
#pragma unroll
        for (int off = 1; off < 64; off <<= 1) {
            tot += __shfl_xor(tot, off);
            pre += __shfl_xor(pre, off);
        }
        if (t == 0) { sh_off = pre; sh_tot = tot; }
    }
    __syncthreads();
    int i = blockIdx.x * 1024 + t;
    if (i < N_NODES) {
        int v = rs[i] + sh_off;
        rs[i] = v;
        cursor[i] = v;
    } else if (i == N_NODES) {
        rs[N_NODES] = sh_tot;
    }
}

__global__ void scatter_kernel(const int* __restrict__ ei, int* __restrict__ cursor,
                               int* __restrict__ csr_src) {
    int e = blockIdx.x * blockDim.x + threadIdx.x;
    if (e >= EP) return;
    int s, d;
    if (e < E_EDGES) { s = ei[e]; d = ei[E_EDGES + e]; } else { s = d = e - E_EDGES; }
    int pos = atomicAdd(cursor + d, 1);
    csr_src[pos] = s;
}

// ---------------- fused softmax + aggregation + bias + ELU + BN stats ----------------
// Wave per dst; 16 edges per iteration in two 8-edge slots (A,B) -> 8 INDEPENDENT
// 16B/lane row-gathers in flight per iteration (R1's paired form had only 4; the
// gather is latency-bound, so MLP is the lever -- R0's 8-deep version ran <=43us).
// Lanes: logit layout eo=lane>>3 (edge), hh=lane&7 (head); agg layout g=lane>>5
// (edge parity), c=lane&31 (16B chunk), hl=c>>2 (owning head).
__global__ __launch_bounds__(256) void attn_kernel(const uint4* __restrict__ h8,
                                                   const float* __restrict__ al_s,
                                                   const float* __restrict__ al_d,
                                                   const int* __restrict__ row_start,
                                                   const int* __restrict__ csr_src,
                                                   const float4* __restrict__ bias4,
                                                   uint4* __restrict__ out8,
                                                   float* __restrict__ part) {
    __shared__ float lds_s[4][256];
    __shared__ float lds_q[4][256];
    int wave = threadIdx.x >> 6;
    int d = blockIdx.x * 4 + wave;
    int lane = threadIdx.x & 63;
    int hh = lane & 7, eo = lane >> 3;
    int g = lane >> 5, c = lane & 31;
    int hl = c >> 2;
    int beg = row_start[d], end = row_start[d + 1];
    float ad = al_d[d * HEADS + hh];
    float ssum = 0.f;
    float acc[8];
#pragma unroll
    for (int t = 0; t < 8; ++t) acc[t] = 0.f;

#define FMA8(v, aj)                                                       \
    {                                                                     \
        acc[0] += aj * bf2f((unsigned short)v.x);                         \
        acc[1] += aj * bf2f((unsigned short)(v.x >> 16));                 \
        acc[2] += aj * bf2f((unsigned short)v.y);                         \
        acc[3] += aj * bf2f((unsigned short)(v.y >> 16));                 \
        acc[4] += aj * bf2f((unsigned short)v.z);                         \
        acc[5] += aj * bf2f((unsigned short)(v.z >> 16));                 \
        acc[6] += aj * bf2f((unsigned short)v.w);                         \
        acc[7] += aj * bf2f((unsigned short)(v.w >> 16));                 \
    }
#define PRE(k, SR, EX, p)                                                 \
    int sj##k = __shfl(SR, (2 * (p) + g) * 8);                            \
    float aj##k = __shfl(EX, (2 * (p) + g) * 8 + hl);                     \
    uint4 w##k = h8[(size_t)sj##k * 32 + c];
#define PAIR(SR, EX, p)                                                   \
    {                                                                     \
        PRE(t, SR, EX, p)                                                 \
        FMA8(w##t, aj##t)                                                 \
    }

    for (int i = beg; i < end; i += 16) {
        int rem = end - i;
        int cntA = rem > 8 ? 8 : rem;
        int cntB = rem > 8 ? (rem > 16 ? 8 : rem - 8) : 0;
        int sregA = 0, sregB = 0;
        float exA = 0.f, exB = 0.f;
        if (eo < cntA) {
            sregA = csr_src[i + eo];
            exA = __expf(lrelu_f(al_s[sregA * HEADS + hh] + ad));
        }
        if (eo < cntB) {
            sregB = csr_src[i + 8 + eo];
            exB = __expf(lrelu_f(al_s[sregB * HEADS + hh] + ad));
        }
        ssum += exA;
        ssum += exB;
        if (rem >= 16) {
            /* fast path: issue all 8 independent gathers, then the FMA chains */
            PRE(0, sregA, exA, 0) PRE(1, sregA, exA, 1)
            PRE(2, sregA, exA, 2) PRE(3, sregA, exA, 3)
            PRE(4, sregB, exB, 0) PRE(5, sregB, exB, 1)
            PRE(6, sregB, exB, 2) PRE(7, sregB, exB, 3)
            FMA8(w0, aj0) FMA8(w1, aj1) FMA8(w2, aj2) FMA8(w3, aj3)
            FMA8(w4, aj4) FMA8(w5, aj5) FMA8(w6, aj6) FMA8(w7, aj7)
        } else {
            int npA = (cntA + 1) >> 1;
            for (int p = 0; p < npA; ++p) PAIR(sregA, exA, p);
            int npB = (cntB + 1) >> 1;
            for (int p = 0; p < npB; ++p) PAIR(sregB, exB, p);
        }
    }
#undef PAIR
#undef PRE
#undef FMA8

    // combine edge-parity halves; reduce denominators across edge slots
#pragma unroll
    for (int t = 0; t < 8; ++t) acc[t] += __shfl_xor(acc[t], 32);
    ssum += __shfl_xor(ssum, 8);
    ssum += __shfl_xor(ssum, 16);
    ssum += __shfl_xor(ssum, 32);
    float inv = 1.f / __shfl(ssum, hl);

    float4 b0 = bias4[c * 2], b1 = bias4[c * 2 + 1];
    float o0 = elu_f(acc[0] * inv + b0.x);
    float o1 = elu_f(acc[1] * inv + b0.y);
    float o2 = elu_f(acc[2] * inv + b0.z);
    float o3 = elu_f(acc[3] * inv + b0.w);
    float o4 = elu_f(acc[4] * inv + b1.x);
    float o5 = elu_f(acc[5] * inv + b1.y);
    float o6 = elu_f(acc[6] * inv + b1.z);
    float o7 = elu_f(acc[7] * inv + b1.w);

    if (g == 0) {
        uint4 ov;
        ov.x = (unsigned)f2bf(o0) | ((unsigned)f2bf(o1) << 16);
        ov.y = (unsigned)f2bf(o2) | ((unsigned)f2bf(o3) << 16);
        ov.z = (unsigned)f2bf(o4) | ((unsigned)f2bf(o5) << 16);
        ov.w = (unsigned)f2bf(o6) | ((unsigned)f2bf(o7) << 16);
        out8[(size_t)d * 32 + c] = ov;
        int cb = c * 8;
        lds_s[wave][cb + 0] = o0; lds_q[wave][cb + 0] = o0 * o0;
        lds_s[wave][cb + 1] = o1; lds_q[wave][cb + 1] = o1 * o1;
        lds_s[wave][cb + 2] = o2; lds_q[wave][cb + 2] = o2 * o2;
        lds_s[wave][cb + 3] = o3; lds_q[wave][cb + 3] = o3 * o3;
        lds_s[wave][cb + 4] = o4; lds_q[wave][cb + 4] = o4 * o4;
        lds_s[wave][cb + 5] = o5; lds_q[wave][cb + 5] = o5 * o5;
        lds_s[wave][cb + 6] = o6; lds_q[wave][cb + 6] = o6 * o6;
        lds_s[wave][cb + 7] = o7; lds_q[wave][cb + 7] = o7 * o7;
    }
    __syncthreads();
    int ch = threadIdx.x;
    float s = lds_s[0][ch] + lds_s[1][ch] + lds_s[2][ch] + lds_s[3][ch];
    float q = lds_q[0][ch] + lds_q[1][ch] + lds_q[2][ch] + lds_q[3][ch];
    float* pb = part + (size_t)(blockIdx.x & (PART_SLOTS - 1)) * 512;
    atomicAdd(pb + ch, s);
    atomicAdd(pb + 256 + ch, q);
}

// ---------------- MLP head via MFMA (bf16 in, BN finalize + scale fused) ----------------
__global__ __launch_bounds__(256) void mlp_mfma(const unsigned short* __restrict__ in,
                                                const float* __restrict__ part,
                                                const float* __restrict__ gam,
                                                const float* __restrict__ bet,
                                                const unsigned short* __restrict__ Wt,
                                                const float* __restrict__ lb1,
                                                const float* __restrict__ lW2,
                                                const float* __restrict__ lb2,
                                                float* __restrict__ out) {
    __shared__ float scs[HC], shs[HC];
    int tid = threadIdx.x;
    {
        int c = tid;
        float s = 0.f, qq = 0.f;
#pragma unroll
        for (int b = 0; b < PART_SLOTS; ++b) {
            s += part[(size_t)b * 512 + c];
            qq += part[(size_t)b * 512 + 256 + c];
        }
        float mn = s / (float)N_NODES;
        float var = qq / (float)N_NODES - mn * mn;
        float istd = rsqrtf(var + BN_EPS);
        float sc = istd * gam[c];
        scs[c] = sc;
        shs[c] = bet[c] - mn * sc;
    }
    __syncthreads();
    int wave = tid >> 6, lane = tid & 63;
    int m = lane & 15, q = lane >> 4;
    int rbase = blockIdx.x * 64 + wave * 16;
    int arow = rbase + m;
    bool valid = arow < N_NODES;
    const unsigned short* ap = in + (size_t)arow * HC;
    f32x4 acc0 = (f32x4){0.f, 0.f, 0.f, 0.f}, acc1 = acc0;
#pragma unroll
    for (int k0 = 0; k0 < HC; k0 += 32) {
        int c0 = k0 + q * 8;
        bf16x8 b0 = *(const bf16x8*)(Wt + (size_t)m * HC + c0);
        bf16x8 b1 = *(const bf16x8*)(Wt + (size_t)(m + 16) * HC + c0);
        bf16x8 a = (bf16x8){0, 0, 0, 0, 0, 0, 0, 0};
        if (valid) {
            uint4 raw = *(const uint4*)(ap + c0);
            float v0 = bf2f((unsigned short)raw.x), v1 = bf2f((unsigned short)(raw.x >> 16));
            float v2 = bf2f((unsigned short)raw.y), v3 = bf2f((unsigned short)(raw.y >> 16));
            float v4 = bf2f((unsigned short)raw.z), v5 = bf2f((unsigned short)(raw.z >> 16));
            float v6 = bf2f((unsigned short)raw.w), v7 = bf2f((unsigned short)(raw.w >> 16));
            float4 s0 = *(const float4*)(scs + c0), s1 = *(const float4*)(scs + c0 + 4);
            float4 t0 = *(const float4*)(shs + c0), t1 = *(const float4*)(shs + c0 + 4);
            a[0] = (short)f2bf(v0 * s0.x + t0.x);
            a[1] = (short)f2bf(v1 * s0.y + t0.y);
            a[2] = (short)f2bf(v2 * s0.z + t0.z);
            a[3] = (short)f2bf(v3 * s0.w + t0.w);
            a[4] = (short)f2bf(v4 * s1.x + t1.x);
            a[5] = (short)f2bf(v5 * s1.y + t1.y);
            a[6] = (short)f2bf(v6 * s1.z + t1.z);
            a[7] = (short)f2bf(v7 * s1.w + t1.w);
        }
        acc0 = __builtin_amdgcn_mfma_f32_16x16x32_bf16(a, b0, acc0, 0, 0, 0);
        acc1 = __builtin_amdgcn_mfma_f32_16x16x32_bf16(a, b1, acc1, 0, 0, 0);
    }
    float w2a = lW2[m], w2b = lW2[m + 16];
    float ba = lb1[m], bb = lb1[m + 16];
#pragma unroll
    for (int r = 0; r < 4; ++r) {
        float v = elu_f(acc0[r] + ba) * w2a + elu_f(acc1[r] + bb) * w2b;
        v += __shfl_xor(v, 1);
        v += __shfl_xor(v, 2);
        v += __shfl_xor(v, 4);
        v += __shfl_xor(v, 8);
        int orow = rbase + q * 4 + r;
        if (m == 0 && orow < N_NODES) out[orow] = v + lb2[0];
    }
}

extern "C" void kernel_launch(void* const* d_in, const int* in_sizes, int n_in,
                              void* d_out, int out_size, void* d_ws, size_t ws_size,
                              hipStream_t stream) {
    const float* x   = (const float*)d_in[0];
    const int*   ei  = (const int*)d_in[1];
    const float* W1  = (const float*)d_in[2];
    const float* a1s = (const float*)d_in[3];
    const float* a1d = (const float*)d_in[4];
    const float* b1  = (const float*)d_in[5];
    const float* g1  = (const float*)d_in[6];
    const float* be1 = (const float*)d_in[7];
    const float* W2  = (const float*)d_in[8];
    const float* a2s = (const float*)d_in[9];
    const float* a2d = (const float*)d_in[10];
    const float* b2  = (const float*)d_in[11];
    const float* g2  = (const float*)d_in[12];
    const float* be2 = (const float*)d_in[13];
    const float* lW1 = (const float*)d_in[14];
    const float* lb1 = (const float*)d_in[15];
    const float* lW2 = (const float*)d_in[16];
    const float* lb2 = (const float*)d_in[17];
    float* out = (float*)d_out;

    char* p = (char*)d_ws;
    auto alloc = [&](size_t bytes) {
        char* r = p;
        p += (bytes + 255) & ~(size_t)255;
        return r;
    };
    unsigned short* h_bf  = (unsigned short*)alloc((size_t)N_NODES * HC * 2);
    unsigned short* o_bf  = (unsigned short*)alloc((size_t)N_NODES * HC * 2);
    unsigned short* wt1   = (unsigned short*)alloc((size_t)IN_CH * HC * 2);
    unsigned short* wt2   = (unsigned short*)alloc((size_t)HC * HC * 2);
    unsigned short* wtm   = (unsigned short*)alloc((size_t)HC * HID * 2);
    float* f_als  = (float*)alloc((size_t)N_NODES * HEADS * 4);
    float* f_ald  = (float*)alloc((size_t)N_NODES * HEADS * 4);
    int*   i_deg  = (int*)alloc((size_t)N_NODES * 4);
    int*   i_rs   = (int*)alloc((size_t)(N_NODES + 1) * 4);
    int*   i_cur  = (int*)alloc((size_t)N_NODES * 4);
    int*   i_src  = (int*)alloc((size_t)EP * 4);
    int*   i_bsum = (int*)alloc((size_t)(SCAN_NB + 1) * 4);
    float* f_part = (float*)alloc((size_t)2 * PART_SLOTS * 512 * 4);

    int eb = (EP + 255) / 256;

    // ---- CSR build (same graph both layers); deg also zeroes BN partials ----
    hipMemsetAsync(i_deg, 0, (size_t)N_NODES * 4, stream);
    deg_kernel<<<eb, 256, 0, stream>>>(ei, i_deg, f_part);
    scan_blk<<<SCAN_NB, 1024, 0, stream>>>(i_deg, i_rs, i_bsum);
    scan_add<<<SCAN_NB, 1024, 0, stream>>>(i_rs, i_cur, i_bsum);
    scatter_kernel<<<eb, 256, 0, stream>>>(ei, i_cur, i_src);

    // ---- all weight conversions, one dispatch ----
    int wtot = IN_CH * HC + HC * HC + HC * HID;
    wt_all_kernel<<<(wtot + 255) / 256, 256, 0, stream>>>(W1, W2, lW1, wt1, wt2, wtm);

    int gblocks = (N_NODES + 127) / 128;
    float* part1 = f_part;
    float* part2 = f_part + (size_t)PART_SLOTS * 512;

    // layer 1: A = x (f32, no BN)
    gemm_mfma<<<gblocks, 512, 0, stream>>>(x, nullptr, wt1, h_bf, f_als, f_ald, a1s, a1d,
                                           N_NODES, IN_CH, nullptr, nullptr, nullptr);
    attn_kernel<<<N_NODES / 4, 256, 0, stream>>>((const uint4*)h_bf, f_als, f_ald,
                                                 i_rs, i_src, (const float4*)b1,
                                                 (uint4*)o_bf, part1);
    // layer 2: A = o_bf (bf16) with BN1 finalized in-kernel from part1
    gemm_mfma<<<gblocks, 512, 0, stream>>>(nullptr, o_bf, wt2, h_bf, f_als, f_ald, a2s, a2d,
                                           N_NODES, HC, part1, g1, be1);
    attn_kernel<<<N_NODES / 4, 256, 0, stream>>>((const uint4*)h_bf, f_als, f_ald,
                                                 i_rs, i_src, (const float4*)b2,
                                                 (uint4*)o_bf, part2);
    // MLP head with BN2 finalized in-kernel from part2
    mlp_mfma<<<(N_NODES + 63) / 64, 256, 0, stream>>>(o_bf, part2, g2, be2, wtm,
                                                      lb1, lW2, lb2, out);
}